// Round 10
// baseline (435.007 us; speedup 1.0000x reference)
//
#include <hip/hip_runtime.h>
#include <math.h>

#define D 128
#define B 256
#define EPSV 1e-5f
#define NREP 64   // BN accumulator replicas (atomic-contention spread)

typedef __attribute__((ext_vector_type(8))) short short8;
typedef __attribute__((ext_vector_type(4))) float f32x4;

static __device__ __forceinline__ ushort f2bf(float f) {
  union { float f; unsigned u; } v; v.f = f;
  unsigned r = (v.u + 0x7fffu + ((v.u >> 16) & 1u)) >> 16;
  return (ushort)r;
}
static __device__ __forceinline__ float bf2f(ushort u) {
  union { unsigned u; float f; } v; v.u = ((unsigned)u) << 16; return v.f;
}
static __device__ __forceinline__ float uaf(unsigned u) {
  union { unsigned u; float f; } v; v.u = u; return v.f;
}
// order-preserving float<->uint encoding for atomicMax on floats (handles -inf)
static __device__ __forceinline__ unsigned encf(float f) {
  union { float f; unsigned u; } v; v.f = f;
  return (v.u & 0x80000000u) ? ~v.u : (v.u | 0x80000000u);
}
static __device__ __forceinline__ float decf(unsigned e) {
  union { unsigned u; float f; } v;
  v.u = (e & 0x80000000u) ? (e & 0x7FFFFFFFu) : ~e;
  return v.f;
}
#define ENC_NEGINF 0x007FFFFFu

// ---------------- init: zero bucket counts + bn + graph-stat accumulators ----------------
static __global__ void init_kernel(int* bcnt, float* bn1s, float* bn1s2,
                                   float* bn2s, float* bn2s2,
                                   float* gsum, unsigned* gmaxE,
                                   float* gcnt, float* gdsum, unsigned* gdmaxE, int N) {
  int i = blockIdx.x * 256 + threadIdx.x;
  if (i < 256) bcnt[i] = 0;
  if (i < NREP * D) { bn1s[i] = 0.f; bn1s2[i] = 0.f; bn2s[i] = 0.f; bn2s2[i] = 0.f; }
  if (i < B * D) { gsum[i] = 0.f; gmaxE[i] = ENC_NEGINF; }
  if (i < B) { gcnt[i] = 0.f; gdsum[i] = 0.f; gdmaxE[i] = ENC_NEGINF; }
}

// ---------------- bucket histogram over dst>>9 (LDS-aggregated, 256 global atomics/blk) ----
static __global__ void __launch_bounds__(256) bhist_kernel(
    const int* __restrict__ dst, int* bcnt, int E) {
  __shared__ int histS[256];
  int t = threadIdx.x;
  int base = blockIdx.x * 4096;
  histS[t] = 0;
  __syncthreads();
#pragma unroll
  for (int k = 0; k < 16; k++) {
    int e = base + k * 256 + t;
    if (e < E) atomicAdd(&histS[dst[e] >> 9], 1);
  }
  __syncthreads();
  int hv = histS[t];
  if (hv > 0) atomicAdd(&bcnt[t], hv);
}

// ---------------- 256-wide scan of bucket counts -> bbase[257], bcur cursors ----------------
static __global__ void bscan_kernel(const int* __restrict__ bcnt, int* bbase, int* bcur) {
  __shared__ int sS[256];
  int t = threadIdx.x;
  int v = bcnt[t];
  sS[t] = v; __syncthreads();
  for (int off = 1; off < 256; off <<= 1) {
    int add = (t >= off) ? sS[t - off] : 0;
    __syncthreads();
    sS[t] += add;
    __syncthreads();
  }
  int incl = sS[t];
  bbase[t + 1] = incl;
  bcur[t] = incl - v;  // exclusive (fillA claim cursor)
  if (t == 0) bbase[0] = 0;
}

// ---------------- node-parallel feature stats + x -> bf16(x*dinv) copy ----------------
// Register-pipelined: 32 independent row loads in flight, then register-only stats loop.
static __global__ void statspart_kernel(const float* __restrict__ x, const int* __restrict__ batch,
                                        const float* __restrict__ dinv,
                                        float* gsum, unsigned* gmaxE,
                                        ushort* __restrict__ x_bf, int N) {
  __shared__ float dS[32];
  __shared__ int bSg[32];
  int t = threadIdx.x;  // 128
  int n0 = blockIdx.x * 32;
  int nend = min(n0 + 32, N);
  int nn = nend - n0;
  if (t < 32) {
    int n = min(n0 + t, N - 1);
    dS[t] = dinv[n];
    bSg[t] = batch[n];
  }
  __syncthreads();
  float v[32];
#pragma unroll
  for (int k = 0; k < 32; k++)
    v[k] = (k < nn) ? x[(size_t)(n0 + k) * D + t] : 0.f;
#pragma unroll
  for (int k = 0; k < 32; k++)
    if (k < nn) x_bf[(size_t)(n0 + k) * D + t] = f2bf(v[k] * dS[k]);
  int curg = bSg[0];
  float s = 0.f, mx = -INFINITY;
#pragma unroll
  for (int k = 0; k < 32; k++) {
    if (k < nn) {
      int g = bSg[k];
      if (g != curg) {
        atomicAdd(&gsum[curg * D + t], s);
        atomicMax(&gmaxE[curg * D + t], encf(mx));
        s = 0.f; mx = -INFINITY; curg = g;
      }
      s += v[k]; mx = fmaxf(mx, v[k]);
    }
  }
  atomicAdd(&gsum[curg * D + t], s);
  atomicMax(&gmaxE[curg * D + t], encf(mx));
}

// ---------------- router MLP + temperature softmax -> gates[B][4] ----------------
static __global__ void router_kernel(
    const float* __restrict__ gsum, const unsigned* __restrict__ gmaxE,
    const float* __restrict__ gcnt, const float* __restrict__ gdsum,
    const unsigned* __restrict__ gdmaxE,
    const float* __restrict__ rw1, const float* __restrict__ rb1,
    const float* __restrict__ rw2, const float* __restrict__ rb2,
    const float* __restrict__ rw3, const float* __restrict__ rb3,
    const float* __restrict__ temp, float* __restrict__ gates) {
  int g = blockIdx.x, t = threadIdx.x;  // 128 threads
  __shared__ float geS[260], h1S[D], h2S[64], scS[4];
  float cntf = fmaxf(gcnt[g], 1.f);
  geS[t] = gsum[g * D + t] / cntf;       // mean pool
  geS[D + t] = decf(gmaxE[g * D + t]);   // max pool
  if (t == 0) {
    geS[256] = cntf;
    geS[257] = gdsum[g] / cntf;
    geS[258] = decf(gdmaxE[g]);
    geS[259] = logf(cntf);
  }
  __syncthreads();
  float a = rb1[t];
  for (int k = 0; k < 260; k++) a += geS[k] * rw1[k * D + t];
  h1S[t] = fmaxf(a, 0.f);
  __syncthreads();
  if (t < 64) { float b = rb2[t]; for (int k = 0; k < D; k++) b += h1S[k] * rw2[k * 64 + t]; h2S[t] = fmaxf(b, 0.f); }
  __syncthreads();
  if (t < 4) { float c = rb3[t]; for (int k = 0; k < 64; k++) c += h2S[k] * rw3[k * 4 + t]; scS[t] = c; }
  __syncthreads();
  if (t == 0) {
    float T = temp[0];
    float q0 = scS[0] / T, q1 = scS[1] / T, q2 = scS[2] / T, q3 = scS[3] / T;
    float m = fmaxf(fmaxf(q0, q1), fmaxf(q2, q3));
    float e0 = expf(q0 - m), e1 = expf(q1 - m), e2 = expf(q2 - m), e3 = expf(q3 - m);
    float inv = 1.f / (e0 + e1 + e2 + e3);
    gates[g * 4 + 0] = e0 * inv; gates[g * 4 + 1] = e1 * inv;
    gates[g * 4 + 2] = e2 * inv; gates[g * 4 + 3] = e3 * inv;
  }
}

// ---------------- per-graph combined expert weights, bf16 TRANSPOSED ----------------
static __global__ void __launch_bounds__(256) wcomb_kernel(
    const float* __restrict__ gates, const float* __restrict__ ew,
    const float* __restrict__ eb, ushort* __restrict__ W_combT,
    float* __restrict__ b_comb) {
  __shared__ ushort wS[128 * 130];
  int g = blockIdx.x, t = threadIdx.x;  // 256 threads
  float g0 = gates[g * 4], g1 = gates[g * 4 + 1], g2 = gates[g * 4 + 2], g3 = gates[g * 4 + 3];
  for (int k = t; k < D * D; k += 256) {
    int d = k >> 7, o = k & 127;  // coalesced read over o
    float v = g0 * ew[k] + g1 * ew[16384 + k] + g2 * ew[32768 + k] + g3 * ew[49152 + k];
    wS[o * 130 + d] = f2bf(v);
  }
  __syncthreads();
  for (int k = t; k < D * D; k += 256) {
    int o = k >> 7, d = k & 127;  // coalesced write over d
    W_combT[(size_t)g * 16384 + k] = wS[o * 130 + d];
  }
  if (t < D)
    b_comb[g * D + t] = g0 * eb[t] + g1 * eb[D + t] + g2 * eb[2 * D + t] + g3 * eb[3 * D + t];
}

// ---------------- FFN weights -> bf16 transposed (k-contiguous) ----------------
static __global__ void prep_kernel(const float* __restrict__ w1, const float* __restrict__ w2,
                                   ushort* __restrict__ w1t, ushort* __restrict__ w2t) {
  int i = blockIdx.x * 256 + threadIdx.x;  // 32768 total
  { int j = i >> 7, d = i & 127; w1t[i] = f2bf(w1[(size_t)d * 256 + j]); }
  { int o = i >> 8, j = i & 255; w2t[i] = f2bf(w2[(size_t)j * 128 + o]); }
}

// ---------------- CSR build pass A: coarse bucket sort by dst>>9, packed int ----------------
// packed edge = (src<<9) | (dst & 511). Assumes NB <= 256 (N <= 131072).
static __global__ void __launch_bounds__(256) fillA_kernel(
    const int* __restrict__ src, const int* __restrict__ dst,
    int* bcur, int* __restrict__ esort, int E) {
  __shared__ int histS[256], startS[256], cursorS[256], gbaseS[256];
  __shared__ int eS[4096];             // 16 KB packed
  __shared__ unsigned char bS[4096];   // bucket of each slot
  int t = threadIdx.x;
  int base = blockIdx.x * 4096;
  int cnt = min(4096, E - base);
  int srcR[16], dstR[16];
  histS[t] = 0;
  __syncthreads();
#pragma unroll
  for (int k = 0; k < 16; k++) {
    int e = base + k * 256 + t;
    if (e < E) { srcR[k] = src[e]; dstR[k] = dst[e]; }
    else dstR[k] = -1;
  }
#pragma unroll
  for (int k = 0; k < 16; k++)
    if (dstR[k] >= 0) atomicAdd(&histS[dstR[k] >> 9], 1);
  __syncthreads();
  int hv = histS[t];
  startS[t] = hv;
  __syncthreads();
  for (int off = 1; off < 256; off <<= 1) {
    int add = (t >= off) ? startS[t - off] : 0;
    __syncthreads();
    startS[t] += add;
    __syncthreads();
  }
  int excl = startS[t] - hv;
  __syncthreads();
  startS[t] = excl;
  cursorS[t] = excl;
  gbaseS[t] = (hv > 0) ? atomicAdd(&bcur[t], hv) : 0;
  __syncthreads();
#pragma unroll
  for (int k = 0; k < 16; k++)
    if (dstR[k] >= 0) {
      int b = dstR[k] >> 9;
      int p = atomicAdd(&cursorS[b], 1);
      eS[p] = (srcR[k] << 9) | (dstR[k] & 511);
      bS[p] = (unsigned char)b;
    }
  __syncthreads();
  for (int k = t; k < cnt; k += 256) {
    int b = bS[k];
    esort[gbaseS[b] + (k - startS[b])] = eS[k];
  }
}

// ---------------- CSR build pass B: per-bucket degree hist + scan + fine fill ----------------
// Produces rowoff, node_deg, dinv AND csr_src — no N-wide global scan needed.
static __global__ void __launch_bounds__(256) fillB_kernel(
    const int* __restrict__ esort, const int* __restrict__ bbase,
    int* __restrict__ rowoff, int* __restrict__ node_deg, float* __restrict__ dinv,
    int* __restrict__ csr_src, int N) {
  __shared__ int degS[512];
  __shared__ int pS[256];
  __shared__ int curS[512];
  int b = blockIdx.x, t = threadIdx.x;
  int n0 = b << 9, n1 = min(n0 + 512, N);
  int nn = n1 - n0;
  int r0 = bbase[b], r1 = bbase[b + 1];
  degS[t] = 0; degS[t + 256] = 0;
  __syncthreads();
  for (int e = r0 + t; e < r1; e += 256) atomicAdd(&degS[esort[e] & 511], 1);
  __syncthreads();
  int d0 = degS[2 * t], d1 = degS[2 * t + 1];
  int ps = d0 + d1;
  pS[t] = ps;
  __syncthreads();
  for (int off = 1; off < 256; off <<= 1) {
    int add = (t >= off) ? pS[t - off] : 0;
    __syncthreads();
    pS[t] += add;
    __syncthreads();
  }
  int pexcl = pS[t] - ps;  // exclusive pair prefix
  int e0 = pexcl, e1 = pexcl + d0;
  curS[2 * t] = r0 + e0;
  curS[2 * t + 1] = r0 + e1;
  int i0 = 2 * t, i1 = 2 * t + 1;
  if (i0 < nn) {
    rowoff[n0 + i0 + 1] = r0 + e0 + d0;
    node_deg[n0 + i0] = d0;
    dinv[n0 + i0] = rsqrtf((float)d0 + 1.f);
  }
  if (i1 < nn) {
    rowoff[n0 + i1 + 1] = r0 + e1 + d1;
    node_deg[n0 + i1] = d1;
    dinv[n0 + i1] = rsqrtf((float)d1 + 1.f);
  }
  if (b == 0 && t == 0) rowoff[0] = 0;
  __syncthreads();
  for (int e = r0 + t; e < r1; e += 256) {
    int v = esort[e];
    int p = atomicAdd(&curS[v & 511], 1);
    csr_src[p] = v >> 9;
  }
}

// ---------------- per-graph degree stats (wave-uniform fold, ex-scanC) ----------------
static __global__ void nodestats_kernel(const int* __restrict__ node_deg,
                                        const int* __restrict__ batch,
                                        float* gcnt, float* gdsum, unsigned* gdmaxE, int N) {
  int i = blockIdx.x * 256 + threadIdx.x;
  int nd = (i < N) ? node_deg[i] : 0;
  int g = batch[min(i, N - 1)];
  float dv = (float)nd;
  int g0w = __shfl(g, 0);
  int waveLast = blockIdx.x * 256 + ((threadIdx.x >> 6) << 6) + 63;
  bool uni = (waveLast < N) && __all(g == g0w);
  if (uni) {
    float s = dv, mx = dv;
    for (int off = 32; off > 0; off >>= 1) { s += __shfl_down(s, off); mx = fmaxf(mx, __shfl_down(mx, off)); }
    if ((threadIdx.x & 63) == 0) {
      atomicAdd(&gcnt[g0w], 64.f);
      atomicAdd(&gdsum[g0w], s);
      atomicMax(&gdmaxE[g0w], encf(mx));
    }
  } else if (i < N) {
    atomicAdd(&gcnt[g], 1.f);
    atomicAdd(&gdsum[g], dv);
    atomicMax(&gdmaxE[g], encf(dv));
  }
}

// ---------------- GCN aggregation: HALF-FEATURE split + XCD group pinning ----------------
// Traffic model: per-XCD fetch = coverage x row-bytes. Splitting each node's 256B row
// into two 128B halves and pinning half h to XCD group h (blockIdx%8 round-robin:
// XCDs 0-3 = half 0, XCDs 4-7 = half 1) halves the row-bytes term:
// predicted x_bf FETCH 190MB -> ~100MB (+13MB csr_src read twice).
// Lane layout: 8 lanes/half-row x 8 edge-slots; 4 dwordx4 gathers in flight.
static __global__ void __launch_bounds__(256) gather_kernel(
    const ushort* __restrict__ xb, const int* __restrict__ rowoff,
    const int* __restrict__ csr_src, const float* __restrict__ dinv,
    ushort* __restrict__ aggB, int N) {
  __shared__ int eS[4][64];
  int t = threadIdx.x, w = t >> 6, l = t & 63;
  int oct = blockIdx.x >> 3, l8 = blockIdx.x & 7;
  int half = l8 >> 2;             // XCDs 0-3 -> half 0, XCDs 4-7 -> half 1
  int grp = oct * 4 + (l8 & 3);   // 4-node group index
  int n = grp * 4 + w;
  if (n >= N) return;
  int h = l >> 3;            // edge sub-slot 0..7
  int c8 = l & 7;            // 16B column within 128B half-row
  int cofs = half * 8 + c8;  // uint4 index within full row
  int r0 = rowoff[n], r1 = rowoff[n + 1];
  float dn = dinv[n];
  const uint4* xb4 = (const uint4*)xb;   // row stride = 16 uint4
  uint4 xo = xb4[(size_t)n * 16 + cofs]; // own (pre-scaled) half-row
  float acc[8];
#pragma unroll
  for (int i = 0; i < 8; i++) acc[i] = 0.f;
  int pads = 0;
#define ACC8(v) { \
    unsigned u0 = (v).x, u1 = (v).y, u2 = (v).z, u3 = (v).w; \
    acc[0] += uaf(u0 << 16); acc[1] += uaf(u0 & 0xFFFF0000u); \
    acc[2] += uaf(u1 << 16); acc[3] += uaf(u1 & 0xFFFF0000u); \
    acc[4] += uaf(u2 << 16); acc[5] += uaf(u2 & 0xFFFF0000u); \
    acc[6] += uaf(u3 << 16); acc[7] += uaf(u3 & 0xFFFF0000u); }
  for (int j0 = r0; j0 < r1; j0 += 64) {
    int cnt = min(64, r1 - j0);
    int cnt8 = (cnt + 7) & ~7;
    pads += cnt8 - cnt;
    eS[w][l] = (j0 + l < r1) ? csr_src[j0 + l] : n;
    int k = 0;
    for (; k + 32 <= cnt8; k += 32) {  // 4 dwordx4 gathers in flight
      int s0 = eS[w][k + h];
      int s1 = eS[w][k + 8 + h];
      int s2 = eS[w][k + 16 + h];
      int s3 = eS[w][k + 24 + h];
      uint4 v0 = xb4[(size_t)s0 * 16 + cofs];
      uint4 v1 = xb4[(size_t)s1 * 16 + cofs];
      uint4 v2 = xb4[(size_t)s2 * 16 + cofs];
      uint4 v3 = xb4[(size_t)s3 * 16 + cofs];
      ACC8(v0); ACC8(v1); ACC8(v2); ACC8(v3);
    }
    if (k + 16 <= cnt8) {
      int s0 = eS[w][k + h];
      int s1 = eS[w][k + 8 + h];
      uint4 v0 = xb4[(size_t)s0 * 16 + cofs];
      uint4 v1 = xb4[(size_t)s1 * 16 + cofs];
      ACC8(v0); ACC8(v1);
      k += 16;
    }
    if (k < cnt8) {
      int s0 = eS[w][k + h];
      uint4 v0 = xb4[(size_t)s0 * 16 + cofs];
      ACC8(v0);
    }
  }
#undef ACC8
#pragma unroll
  for (int i = 0; i < 8; i++) {  // fold 8 edge-slot groups
    acc[i] += __shfl_down(acc[i], 32);
    acc[i] += __shfl_down(acc[i], 16);
    acc[i] += __shfl_down(acc[i], 8);
  }
  if (l < 8) {
    float wn = 1.f - (float)pads;  // self term minus pad over-count
    float xf[8];
    xf[0] = uaf(xo.x << 16); xf[1] = uaf(xo.x & 0xFFFF0000u);
    xf[2] = uaf(xo.y << 16); xf[3] = uaf(xo.y & 0xFFFF0000u);
    xf[4] = uaf(xo.z << 16); xf[5] = uaf(xo.z & 0xFFFF0000u);
    xf[6] = uaf(xo.w << 16); xf[7] = uaf(xo.w & 0xFFFF0000u);
    unsigned o[4];
#pragma unroll
    for (int i = 0; i < 4; i++) {
      unsigned lo = f2bf(dn * (acc[2 * i] + wn * xf[2 * i]));
      unsigned hi = f2bf(dn * (acc[2 * i + 1] + wn * xf[2 * i + 1]));
      o[i] = lo | (hi << 16);
    }
    uint4 ov; ov.x = o[0]; ov.y = o[1]; ov.z = o[2]; ov.w = o[3];
    ((uint4*)aggB)[(size_t)n * 16 + cofs] = ov;
  }
}

// ---------------- gated expert combine + residual (MFMA bf16), 4 waves, 32 cols/wave ----
// Ballot-mask segments; W panel staged to LDS; XCD-chunk-swizzled tile index.
static __global__ void __launch_bounds__(256) expert_kernel(
    const ushort* __restrict__ aggB, const float* __restrict__ x, const int* __restrict__ batch,
    const ushort* __restrict__ W_combT, const float* __restrict__ b_comb,
    ushort* __restrict__ hB, float* bn1s, float* bn1s2, int N) {
  __shared__ __align__(16) ushort aggS[64 * 136];   // 17 KB
  __shared__ __align__(16) ushort wS[128 * 136];    // 34 KB (W panel, per segment)
  __shared__ int bS[64];
  int t = threadIdx.x;
  // ---- XCD-aware bijective tile swizzle (8 XCDs, round-robin hw dispatch) ----
  int nwg = gridDim.x;
  int q = nwg >> 3, r = nwg & 7;
  int xcd = blockIdx.x & 7, ix = blockIdx.x >> 3;
  int tilei = (xcd < r) ? (xcd * (q + 1) + ix) : (r * (q + 1) + (xcd - r) * q + ix);
  int n0 = tilei * 64;
  int tile = min(64, N - n0);
  for (int k = t; k < 64 * 16; k += 256) {  // short8 copies, no convert
    int i = k >> 4, c = (k & 15) * 8;
    short8 v = (short8){0, 0, 0, 0, 0, 0, 0, 0};
    if (i < tile) v = *(const short8*)&aggB[(size_t)(n0 + i) * D + c];
    *(short8*)&aggS[i * 136 + c] = v;
  }
  if (t < 64) bS[t] = batch[min(n0 + t, N - 1)];
  __syncthreads();
  int w = t >> 6, ln = t & 15, quad = (t & 63) >> 4, l64 = t & 63;
  // ---- segment mask: one parallel LDS read + shfl + ballot (all-register after) ----
  int myg = bS[l64];
  int gnext = __shfl_down(myg, 1);
  unsigned long long bmask = __ballot(l64 == 63 || myg != gnext);
  float s[2] = {0.f, 0.f}, s2[2] = {0.f, 0.f};
  int mstart = 0;
  while (mstart < tile) {
    int g = __shfl(myg, mstart);                 // wave-uniform broadcast, no LDS
    int mend = mstart + __ffsll((unsigned long long)(bmask >> mstart));  // 1-based ffs
    if (mend > tile) mend = tile;
    // ---- stage W panel (32 KB) for this segment's graph into LDS ----
    __syncthreads();  // protect wS from previous segment's readers
    const ushort* Wg = W_combT + (size_t)g * 16384;
    for (int k = t; k < 128 * 16; k += 256) {
      int o = k >> 4, c = (k & 15) * 8;
      *(short8*)&wS[o * 136 + c] = *(const short8*)&Wg[(size_t)o * 128 + c];
    }
    __syncthreads();
    f32x4 acc[4][2];
#pragma unroll
    for (int mi = 0; mi < 4; mi++)
#pragma unroll
      for (int ni = 0; ni < 2; ni++) acc[mi][ni] = (f32x4){0.f, 0.f, 0.f, 0.f};
#pragma unroll
    for (int ks = 0; ks < 4; ks++) {
      int kk = ks * 32 + quad * 8;
      short8 a[4], b[2];
#pragma unroll
      for (int mi = 0; mi < 4; mi++) a[mi] = *(const short8*)&aggS[(mi * 16 + ln) * 136 + kk];
#pragma unroll
      for (int ni = 0; ni < 2; ni++) b[ni] = *(const short8*)&wS[(w * 32 + ni * 16 + ln) * 136 + kk];
#pragma unroll
      for (int mi = 0; mi < 4; mi++)
#pragma unroll
        for (int ni = 0; ni < 2; ni++)
          acc[mi][ni] = __builtin_amdgcn_mfma_f32_16x16x32_bf16(a[mi], b[ni], acc[mi][ni], 0, 0, 0);
    }
    float bias[2];
#pragma unroll
    for (int ni = 0; ni < 2; ni++) bias[ni] = b_comb[g * D + w * 32 + ni * 16 + ln];
#pragma unroll
    for (int mi = 0; mi < 4; mi++)
#pragma unroll
      for (int r2_ = 0; r2_ < 4; r2_++) {
        int m = mi * 16 + quad * 4 + r2_;
        if (m >= mstart && m < mend) {
          size_t rowoff_ = (size_t)(n0 + m) * D;
#pragma unroll
          for (int ni = 0; ni < 2; ni++) {
            int o = w * 32 + ni * 16 + ln;
            float hv = x[rowoff_ + o] + acc[mi][ni][r2_] + bias[ni];
            hB[rowoff_ + o] = f2bf(hv);
            s[ni] += hv; s2[ni] += hv * hv;
          }
        }
      }
    mstart = mend;
  }
#pragma unroll
  for (int ni = 0; ni < 2; ni++) {
    s[ni] += __shfl_down(s[ni], 32);  s[ni] += __shfl_down(s[ni], 16);
    s2[ni] += __shfl_down(s2[ni], 32); s2[ni] += __shfl_down(s2[ni], 16);
  }
  if (quad == 0) {
    int slot = (tilei & (NREP - 1)) * D;
#pragma unroll
    for (int ni = 0; ni < 2; ni++) {
      int o = w * 32 + ni * 16 + ln;
      atomicAdd(&bn1s[slot + o], s[ni]);
      atomicAdd(&bn1s2[slot + o], s2[ni]);
    }
  }
}

// ---------------- bn finalize: reduce 64 replicas -> fused scale/shift ----------------
static __global__ void bnfin_kernel(const float* s, const float* s2,
                                    const float* __restrict__ g, const float* __restrict__ b,
                                    float* sc, float* sh, float invN) {
  int t = threadIdx.x;
  if (t < D) {
    float st = 0.f, s2t = 0.f;
    for (int k = 0; k < NREP; k++) { st += s[k * D + t]; s2t += s2[k * D + t]; }
    float m = st * invN;
    float var = s2t * invN - m * m;
    float rstd = rsqrtf(var + EPSV);
    float scv = rstd * g[t];
    sc[t] = scv;
    sh[t] = b[t] - m * scv;
  }
}

// ---------------- FFN (MFMA bf16), M=64, 8 waves, in-place on hB ----------------
static __global__ void __launch_bounds__(512, 4) ffn_kernel(
    ushort* __restrict__ hB, const float* __restrict__ sc1, const float* __restrict__ sh1,
    const ushort* __restrict__ w1t, const float* __restrict__ fb1,
    const ushort* __restrict__ w2t, const float* __restrict__ fb2,
    float* bn2s, float* bn2s2, int N) {
  __shared__ __align__(16) ushort kvnS[64 * 136];   // 17 KB
  __shared__ __align__(16) ushort hidS[64 * 264];   // 34 KB
  int t = threadIdx.x, n0 = blockIdx.x * 64;
  int tile = min(64, N - n0);
  for (int k = t; k < 64 * 16; k += 512) {   // uint4 loads: 8 bf16 per iteration
    int i = k >> 4, c = (k & 15) * 8;
    ushort o[8];
    if (i < tile) {
      uint4 hv = *(const uint4*)&hB[(size_t)(n0 + i) * D + c];
      unsigned uu[4] = {hv.x, hv.y, hv.z, hv.w};
#pragma unroll
      for (int j = 0; j < 4; j++) {
        float lo = uaf(uu[j] << 16) * sc1[c + 2 * j] + sh1[c + 2 * j];
        float hi = uaf(uu[j] & 0xFFFF0000u) * sc1[c + 2 * j + 1] + sh1[c + 2 * j + 1];
        o[2 * j] = f2bf(lo); o[2 * j + 1] = f2bf(hi);
      }
    } else {
#pragma unroll
      for (int j = 0; j < 8; j++) o[j] = 0;
    }
    *(short8*)&kvnS[i * 136 + c] = *(short8*)o;
  }
  __syncthreads();
  int w = t >> 6, ln = t & 15, quad = (t & 63) >> 4;
  // ---- GEMM1: hidden[64x256] = kvn[64x128] @ w1[128x256]; wave w -> cols w*32..w*32+31
  f32x4 acc1[4][2];
#pragma unroll
  for (int mi = 0; mi < 4; mi++)
#pragma unroll
    for (int ni = 0; ni < 2; ni++) acc1[mi][ni] = (f32x4){0.f, 0.f, 0.f, 0.f};
#pragma unroll
  for (int ks = 0; ks < 4; ks++) {
    int kk = ks * 32 + quad * 8;
    short8 a[4], b[2];
#pragma unroll
    for (int mi = 0; mi < 4; mi++) a[mi] = *(const short8*)&kvnS[(mi * 16 + ln) * 136 + kk];
#pragma unroll
    for (int ni = 0; ni < 2; ni++) b[ni] = *(const short8*)&w1t[(size_t)(w * 32 + ni * 16 + ln) * 128 + kk];
#pragma unroll
    for (int mi = 0; mi < 4; mi++)
#pragma unroll
      for (int ni = 0; ni < 2; ni++)
        acc1[mi][ni] = __builtin_amdgcn_mfma_f32_16x16x32_bf16(a[mi], b[ni], acc1[mi][ni], 0, 0, 0);
  }
  float bias1[2];
#pragma unroll
  for (int ni = 0; ni < 2; ni++) bias1[ni] = fb1[w * 32 + ni * 16 + ln];
#pragma unroll
  for (int mi = 0; mi < 4; mi++)
#pragma unroll
    for (int ni = 0; ni < 2; ni++)
#pragma unroll
      for (int r = 0; r < 4; r++) {
        int mrow = mi * 16 + quad * 4 + r;
        int j = w * 32 + ni * 16 + ln;
        hidS[mrow * 264 + j] = f2bf(fmaxf(acc1[mi][ni][r] + bias1[ni], 0.f));
      }
  __syncthreads();
  // ---- GEMM2: out[64x128] = hidden[64x256] @ w2[256x128]; wave w -> cols w*16..w*16+15
  int o = w * 16 + ln;
  f32x4 acc2[4];
#pragma unroll
  for (int mi = 0; mi < 4; mi++) acc2[mi] = (f32x4){0.f, 0.f, 0.f, 0.f};
#pragma unroll
  for (int ks = 0; ks < 8; ks++) {
    int kk = ks * 32 + quad * 8;
    short8 a[4], b;
#pragma unroll
    for (int mi = 0; mi < 4; mi++) a[mi] = *(const short8*)&hidS[(mi * 16 + ln) * 264 + kk];
    b = *(const short8*)&w2t[(size_t)o * 256 + kk];
#pragma unroll
    for (int mi = 0; mi < 4; mi++)
      acc2[mi] = __builtin_amdgcn_mfma_f32_16x16x32_bf16(a[mi], b, acc2[mi], 0, 0, 0);
  }
  float bias2 = fb2[o];
  float s = 0.f, s2 = 0.f;
#pragma unroll
  for (int mi = 0; mi < 4; mi++)
#pragma unroll
    for (int r = 0; r < 4; r++) {
      int mrow = mi * 16 + quad * 4 + r;
      if (mrow < tile) {
        size_t ro = (size_t)(n0 + mrow) * D;
        float v = bf2f(kvnS[mrow * 136 + o]) + acc2[mi][r] + bias2;
        hB[ro + o] = f2bf(v);  // in-place: tile already staged in kvnS
        s += v; s2 += v * v;
      }
    }
  s += __shfl_down(s, 32);  s += __shfl_down(s, 16);
  s2 += __shfl_down(s2, 32); s2 += __shfl_down(s2, 16);
  if (quad == 0) {
    int slot = (blockIdx.x & (NREP - 1)) * D;
    atomicAdd(&bn2s[slot + o], s);
    atomicAdd(&bn2s2[slot + o], s2);
  }
}

// ---------------- final bn2 apply: bf16 in -> fp32 out, 8 elems/thread ----------------
static __global__ void bnapply_kernel(const ushort* __restrict__ hB, float* __restrict__ out,
                                      const float* __restrict__ sc, const float* __restrict__ sh,
                                      int total8) {
  int i = blockIdx.x * 256 + threadIdx.x;  // 8-element groups
  if (i < total8) {
    int c = (i * 8) & 127;
    uint4 hv = ((const uint4*)hB)[i];
    unsigned uu[4] = {hv.x, hv.y, hv.z, hv.w};
    float4 o0, o1;
    o0.x = uaf(uu[0] << 16) * sc[c] + sh[c];
    o0.y = uaf(uu[0] & 0xFFFF0000u) * sc[c + 1] + sh[c + 1];
    o0.z = uaf(uu[1] << 16) * sc[c + 2] + sh[c + 2];
    o0.w = uaf(uu[1] & 0xFFFF0000u) * sc[c + 3] + sh[c + 3];
    o1.x = uaf(uu[2] << 16) * sc[c + 4] + sh[c + 4];
    o1.y = uaf(uu[2] & 0xFFFF0000u) * sc[c + 5] + sh[c + 5];
    o1.z = uaf(uu[3] << 16) * sc[c + 6] + sh[c + 6];
    o1.w = uaf(uu[3] & 0xFFFF0000u) * sc[c + 7] + sh[c + 7];
    ((float4*)out)[i * 2] = o0;
    ((float4*)out)[i * 2 + 1] = o1;
  }
}

extern "C" void kernel_launch(void* const* d_in, const int* in_sizes, int n_in,
                              void* d_out, int out_size, void* d_ws, size_t ws_size,
                              hipStream_t stream) {
  (void)n_in; (void)out_size; (void)ws_size;
  const float* x    = (const float*)d_in[0];
  const int*   ei   = (const int*)d_in[1];
  const int*   batch= (const int*)d_in[2];
  const float* temp = (const float*)d_in[3];
  const float* rw1  = (const float*)d_in[4];
  const float* rb1  = (const float*)d_in[5];
  const float* rw2  = (const float*)d_in[6];
  const float* rb2  = (const float*)d_in[7];
  const float* rw3  = (const float*)d_in[8];
  const float* rb3  = (const float*)d_in[9];
  const float* ew   = (const float*)d_in[10];
  const float* eb   = (const float*)d_in[11];
  const float* bn1g = (const float*)d_in[12];
  const float* bn1b = (const float*)d_in[13];
  const float* fw1  = (const float*)d_in[14];
  const float* fb1  = (const float*)d_in[15];
  const float* fw2  = (const float*)d_in[16];
  const float* fb2  = (const float*)d_in[17];
  const float* bn2g = (const float*)d_in[18];
  const float* bn2b = (const float*)d_in[19];

  int N = in_sizes[0] / D;
  int E = in_sizes[1] / 2;
  const int* src = ei;
  const int* dst = ei + E;

  // d_out doubles as scratch: x_bf | aggB (2 x N*D*2 bytes = exactly out size);
  // both dead before bnapply overwrites d_out with the fp32 result.
  ushort* x_bf = (ushort*)d_out;
  ushort* aggB = (ushort*)((char*)d_out + (size_t)N * D * 2);

  char* p = (char*)d_ws;
  auto alloc = [&](size_t bytes) -> void* {
    void* r = (void*)p;
    p += (bytes + 255) & ~(size_t)255;
    return r;
  };
  int NB = (N + 511) >> 9;  // 512-node buckets (assumes NB <= 256)
  int*   node_deg = (int*)alloc((size_t)N * 4);
  int*   rowoff   = (int*)alloc(((size_t)N + 1) * 4);
  int*   csr_src  = (int*)alloc((size_t)E * 4);
  int*   esort    = (int*)alloc((size_t)E * 4);
  int*   bcnt     = (int*)alloc(256 * 4);
  int*   bbase    = (int*)alloc(257 * 4);
  int*   bcur     = (int*)alloc(256 * 4);
  float* dinv     = (float*)alloc((size_t)N * 4);
  ushort* hB      = (ushort*)alloc((size_t)N * D * 2);
  float* gsum     = (float*)alloc((size_t)B * D * 4);
  unsigned* gmaxE = (unsigned*)alloc((size_t)B * D * 4);
  float* gcnt     = (float*)alloc((size_t)B * 4);
  float* gdsum    = (float*)alloc((size_t)B * 4);
  unsigned* gdmaxE= (unsigned*)alloc((size_t)B * 4);
  float* gates    = (float*)alloc((size_t)B * 4 * 4);
  float* b_comb   = (float*)alloc((size_t)B * D * 4);
  float* bn1s     = (float*)alloc((size_t)NREP * D * 4);
  float* bn1s2    = (float*)alloc((size_t)NREP * D * 4);
  float* sc1      = (float*)alloc(D * 4);
  float* sh1      = (float*)alloc(D * 4);
  float* bn2s     = (float*)alloc((size_t)NREP * D * 4);
  float* bn2s2    = (float*)alloc((size_t)NREP * D * 4);
  float* sc2      = (float*)alloc(D * 4);
  float* sh2      = (float*)alloc(D * 4);
  ushort* W_combT = (ushort*)alloc((size_t)B * D * D * 2);
  ushort* w1t     = (ushort*)alloc((size_t)D * 256 * 2);
  ushort* w2t     = (ushort*)alloc((size_t)D * 256 * 2);

  init_kernel<<<(N + 255) / 256, 256, 0, stream>>>(bcnt, bn1s, bn1s2, bn2s, bn2s2,
                                                   gsum, gmaxE, gcnt, gdsum, gdmaxE, N);
  prep_kernel<<<128, 256, 0, stream>>>(fw1, fw2, w1t, w2t);
  bhist_kernel<<<(E + 4095) / 4096, 256, 0, stream>>>(dst, bcnt, E);
  bscan_kernel<<<1, 256, 0, stream>>>(bcnt, bbase, bcur);
  fillA_kernel<<<(E + 4095) / 4096, 256, 0, stream>>>(src, dst, bcur, esort, E);
  fillB_kernel<<<NB, 256, 0, stream>>>(esort, bbase, rowoff, node_deg, dinv, csr_src, N);
  nodestats_kernel<<<(N + 255) / 256, 256, 0, stream>>>(node_deg, batch, gcnt, gdsum, gdmaxE, N);
  // statspart needs dinv (x_bf is pre-scaled by dinv)
  statspart_kernel<<<(N + 31) / 32, 128, 0, stream>>>(x, batch, dinv, gsum, gmaxE, x_bf, N);
  router_kernel<<<B, 128, 0, stream>>>(gsum, gmaxE, gcnt, gdsum, gdmaxE,
                                       rw1, rb1, rw2, rb2, rw3, rb3, temp, gates);
  wcomb_kernel<<<B, 256, 0, stream>>>(gates, ew, eb, W_combT, b_comb);
  // half-feature split gather: octets of 8 blocks (4 node-groups x 2 halves)
  int NB4 = (N + 3) / 4;
  int octs = (NB4 + 3) / 4;
  gather_kernel<<<octs * 8, 256, 0, stream>>>(x_bf, rowoff, csr_src, dinv, aggB, N);
  int nb64 = (N + 63) / 64;
  expert_kernel<<<nb64, 256, 0, stream>>>(aggB, x, batch, W_combT, b_comb, hB, bn1s, bn1s2, N);
  bnfin_kernel<<<1, 128, 0, stream>>>(bn1s, bn1s2, bn1g, bn1b, sc1, sh1, 1.0f / (float)N);
  ffn_kernel<<<nb64, 512, 0, stream>>>(hB, sc1, sh1, w1t, fb1, w2t, fb2, bn2s, bn2s2, N);
  bnfin_kernel<<<1, 128, 0, stream>>>(bn2s, bn2s2, bn2g, bn2b, sc2, sh2, 1.0f / (float)N);
  int total8 = N * D / 8;
  bnapply_kernel<<<(total8 + 255) / 256, 256, 0, stream>>>(hB, (float*)d_out, sc2, sh2, total8);
}

// Round 12
// 416.678 us; speedup vs baseline: 1.0440x; 1.0440x over previous
//
#include <hip/hip_runtime.h>
#include <math.h>

#define D 128
#define B 256
#define EPSV 1e-5f
#define NREP 64   // BN accumulator replicas (atomic-contention spread)

typedef __attribute__((ext_vector_type(8))) short short8;
typedef __attribute__((ext_vector_type(4))) float f32x4;

static __device__ __forceinline__ ushort f2bf(float f) {
  union { float f; unsigned u; } v; v.f = f;
  unsigned r = (v.u + 0x7fffu + ((v.u >> 16) & 1u)) >> 16;
  return (ushort)r;
}
static __device__ __forceinline__ float bf2f(ushort u) {
  union { unsigned u; float f; } v; v.u = ((unsigned)u) << 16; return v.f;
}
static __device__ __forceinline__ float uaf(unsigned u) {
  union { unsigned u; float f; } v; v.u = u; return v.f;
}
// order-preserving float<->uint encoding for atomicMax on floats (handles -inf)
static __device__ __forceinline__ unsigned encf(float f) {
  union { float f; unsigned u; } v; v.f = f;
  return (v.u & 0x80000000u) ? ~v.u : (v.u | 0x80000000u);
}
static __device__ __forceinline__ float decf(unsigned e) {
  union { unsigned u; float f; } v;
  v.u = (e & 0x80000000u) ? (e & 0x7FFFFFFFu) : ~e;
  return v.f;
}
#define ENC_NEGINF 0x007FFFFFu

// ---------------- setup: init accumulators | FFN weight transpose (pure writes, safe fuse) ----
// NOTE: bhist must NOT be fused here — it atomically accumulates into bcnt, which this
// kernel zeroes; same-launch block ordering is undefined across XCDs (caught by tripwire R11).
static __global__ void __launch_bounds__(256) setup_kernel(
    int* bcnt, float* bn1s, float* bn1s2, float* bn2s, float* bn2s2,
    float* gsum, unsigned* gmaxE, float* gcnt, float* gdsum, unsigned* gdmaxE,
    const float* __restrict__ w1, const float* __restrict__ w2,
    ushort* __restrict__ w1t, ushort* __restrict__ w2t,
    int N, int nbInit) {
  int b = blockIdx.x, t = threadIdx.x;
  if (b < nbInit) {
    int i = b * 256 + t;
    if (i < 256) bcnt[i] = 0;
    if (i < NREP * D) { bn1s[i] = 0.f; bn1s2[i] = 0.f; bn2s[i] = 0.f; bn2s2[i] = 0.f; }
    if (i < B * D) { gsum[i] = 0.f; gmaxE[i] = ENC_NEGINF; }
    if (i < B) { gcnt[i] = 0.f; gdsum[i] = 0.f; gdmaxE[i] = ENC_NEGINF; }
  } else {
    int i = (b - nbInit) * 256 + t;  // 32768 total
    { int j = i >> 7, d = i & 127; w1t[i] = f2bf(w1[(size_t)d * 256 + j]); }
    { int o = i >> 8, j = i & 255; w2t[i] = f2bf(w2[(size_t)j * 128 + o]); }
  }
}

// ---------------- bucket histogram over dst>>9 (LDS-aggregated, 256 global atomics/blk) ----
static __global__ void __launch_bounds__(256) bhist_kernel(
    const int* __restrict__ dst, int* bcnt, int E) {
  __shared__ int histS[256];
  int t = threadIdx.x;
  int base = blockIdx.x * 4096;
  histS[t] = 0;
  __syncthreads();
#pragma unroll
  for (int k = 0; k < 16; k++) {
    int e = base + k * 256 + t;
    if (e < E) atomicAdd(&histS[dst[e] >> 9], 1);
  }
  __syncthreads();
  int hv = histS[t];
  if (hv > 0) atomicAdd(&bcnt[t], hv);
}

// ---------------- 256-wide scan of bucket counts -> bbase[257], bcur cursors ----------------
static __global__ void bscan_kernel(const int* __restrict__ bcnt, int* bbase, int* bcur) {
  __shared__ int sS[256];
  int t = threadIdx.x;
  int v = bcnt[t];
  sS[t] = v; __syncthreads();
  for (int off = 1; off < 256; off <<= 1) {
    int add = (t >= off) ? sS[t - off] : 0;
    __syncthreads();
    sS[t] += add;
    __syncthreads();
  }
  int incl = sS[t];
  bbase[t + 1] = incl;
  bcur[t] = incl - v;  // exclusive (fillA claim cursor)
  if (t == 0) bbase[0] = 0;
}

// ---------------- node-parallel feature stats + x -> bf16(x*dinv) copy ----------------
// Register-pipelined: 32 independent row loads in flight, then register-only stats loop.
static __global__ void statspart_kernel(const float* __restrict__ x, const int* __restrict__ batch,
                                        const float* __restrict__ dinv,
                                        float* gsum, unsigned* gmaxE,
                                        ushort* __restrict__ x_bf, int N) {
  __shared__ float dS[32];
  __shared__ int bSg[32];
  int t = threadIdx.x;  // 128
  int n0 = blockIdx.x * 32;
  int nend = min(n0 + 32, N);
  int nn = nend - n0;
  if (t < 32) {
    int n = min(n0 + t, N - 1);
    dS[t] = dinv[n];
    bSg[t] = batch[n];
  }
  __syncthreads();
  float v[32];
#pragma unroll
  for (int k = 0; k < 32; k++)
    v[k] = (k < nn) ? x[(size_t)(n0 + k) * D + t] : 0.f;
#pragma unroll
  for (int k = 0; k < 32; k++)
    if (k < nn) x_bf[(size_t)(n0 + k) * D + t] = f2bf(v[k] * dS[k]);
  int curg = bSg[0];
  float s = 0.f, mx = -INFINITY;
#pragma unroll
  for (int k = 0; k < 32; k++) {
    if (k < nn) {
      int g = bSg[k];
      if (g != curg) {
        atomicAdd(&gsum[curg * D + t], s);
        atomicMax(&gmaxE[curg * D + t], encf(mx));
        s = 0.f; mx = -INFINITY; curg = g;
      }
      s += v[k]; mx = fmaxf(mx, v[k]);
    }
  }
  atomicAdd(&gsum[curg * D + t], s);
  atomicMax(&gmaxE[curg * D + t], encf(mx));
}

// ---------------- router MLP + temperature softmax -> gates[B][4] ----------------
static __global__ void router_kernel(
    const float* __restrict__ gsum, const unsigned* __restrict__ gmaxE,
    const float* __restrict__ gcnt, const float* __restrict__ gdsum,
    const unsigned* __restrict__ gdmaxE,
    const float* __restrict__ rw1, const float* __restrict__ rb1,
    const float* __restrict__ rw2, const float* __restrict__ rb2,
    const float* __restrict__ rw3, const float* __restrict__ rb3,
    const float* __restrict__ temp, float* __restrict__ gates) {
  int g = blockIdx.x, t = threadIdx.x;  // 128 threads
  __shared__ float geS[260], h1S[D], h2S[64], scS[4];
  float cntf = fmaxf(gcnt[g], 1.f);
  geS[t] = gsum[g * D + t] / cntf;       // mean pool
  geS[D + t] = decf(gmaxE[g * D + t]);   // max pool
  if (t == 0) {
    geS[256] = cntf;
    geS[257] = gdsum[g] / cntf;
    geS[258] = decf(gdmaxE[g]);
    geS[259] = logf(cntf);
  }
  __syncthreads();
  float a = rb1[t];
  for (int k = 0; k < 260; k++) a += geS[k] * rw1[k * D + t];
  h1S[t] = fmaxf(a, 0.f);
  __syncthreads();
  if (t < 64) { float b = rb2[t]; for (int k = 0; k < D; k++) b += h1S[k] * rw2[k * 64 + t]; h2S[t] = fmaxf(b, 0.f); }
  __syncthreads();
  if (t < 4) { float c = rb3[t]; for (int k = 0; k < 64; k++) c += h2S[k] * rw3[k * 4 + t]; scS[t] = c; }
  __syncthreads();
  if (t == 0) {
    float T = temp[0];
    float q0 = scS[0] / T, q1 = scS[1] / T, q2 = scS[2] / T, q3 = scS[3] / T;
    float m = fmaxf(fmaxf(q0, q1), fmaxf(q2, q3));
    float e0 = expf(q0 - m), e1 = expf(q1 - m), e2 = expf(q2 - m), e3 = expf(q3 - m);
    float inv = 1.f / (e0 + e1 + e2 + e3);
    gates[g * 4 + 0] = e0 * inv; gates[g * 4 + 1] = e1 * inv;
    gates[g * 4 + 2] = e2 * inv; gates[g * 4 + 3] = e3 * inv;
  }
}

// ---------------- per-graph combined expert weights, bf16 TRANSPOSED ----------------
static __global__ void __launch_bounds__(256) wcomb_kernel(
    const float* __restrict__ gates, const float* __restrict__ ew,
    const float* __restrict__ eb, ushort* __restrict__ W_combT,
    float* __restrict__ b_comb) {
  __shared__ ushort wS[128 * 130];
  int g = blockIdx.x, t = threadIdx.x;  // 256 threads
  float g0 = gates[g * 4], g1 = gates[g * 4 + 1], g2 = gates[g * 4 + 2], g3 = gates[g * 4 + 3];
  for (int k = t; k < D * D; k += 256) {
    int d = k >> 7, o = k & 127;  // coalesced read over o
    float v = g0 * ew[k] + g1 * ew[16384 + k] + g2 * ew[32768 + k] + g3 * ew[49152 + k];
    wS[o * 130 + d] = f2bf(v);
  }
  __syncthreads();
  for (int k = t; k < D * D; k += 256) {
    int o = k >> 7, d = k & 127;  // coalesced write over d
    W_combT[(size_t)g * 16384 + k] = wS[o * 130 + d];
  }
  if (t < D)
    b_comb[g * D + t] = g0 * eb[t] + g1 * eb[D + t] + g2 * eb[2 * D + t] + g3 * eb[3 * D + t];
}

// ---------------- CSR build pass A: coarse bucket sort by dst>>9, packed int ----------------
// packed edge = (src<<9) | (dst & 511). Assumes NB <= 256 (N <= 131072).
static __global__ void __launch_bounds__(256) fillA_kernel(
    const int* __restrict__ src, const int* __restrict__ dst,
    int* bcur, int* __restrict__ esort, int E) {
  __shared__ int histS[256], startS[256], cursorS[256], gbaseS[256];
  __shared__ int eS[4096];             // 16 KB packed
  __shared__ unsigned char bS[4096];   // bucket of each slot
  int t = threadIdx.x;
  int base = blockIdx.x * 4096;
  int cnt = min(4096, E - base);
  int srcR[16], dstR[16];
  histS[t] = 0;
  __syncthreads();
#pragma unroll
  for (int k = 0; k < 16; k++) {
    int e = base + k * 256 + t;
    if (e < E) { srcR[k] = src[e]; dstR[k] = dst[e]; }
    else dstR[k] = -1;
  }
#pragma unroll
  for (int k = 0; k < 16; k++)
    if (dstR[k] >= 0) atomicAdd(&histS[dstR[k] >> 9], 1);
  __syncthreads();
  int hv = histS[t];
  startS[t] = hv;
  __syncthreads();
  for (int off = 1; off < 256; off <<= 1) {
    int add = (t >= off) ? startS[t - off] : 0;
    __syncthreads();
    startS[t] += add;
    __syncthreads();
  }
  int excl = startS[t] - hv;
  __syncthreads();
  startS[t] = excl;
  cursorS[t] = excl;
  gbaseS[t] = (hv > 0) ? atomicAdd(&bcur[t], hv) : 0;
  __syncthreads();
#pragma unroll
  for (int k = 0; k < 16; k++)
    if (dstR[k] >= 0) {
      int b = dstR[k] >> 9;
      int p = atomicAdd(&cursorS[b], 1);
      eS[p] = (srcR[k] << 9) | (dstR[k] & 511);
      bS[p] = (unsigned char)b;
    }
  __syncthreads();
  for (int k = t; k < cnt; k += 256) {
    int b = bS[k];
    esort[gbaseS[b] + (k - startS[b])] = eS[k];
  }
}

// ---------------- CSR build pass B: per-bucket degree hist + scan + fine fill ----------------
// Produces rowoff, node_deg, dinv AND csr_src — no N-wide global scan needed.
static __global__ void __launch_bounds__(256) fillB_kernel(
    const int* __restrict__ esort, const int* __restrict__ bbase,
    int* __restrict__ rowoff, int* __restrict__ node_deg, float* __restrict__ dinv,
    int* __restrict__ csr_src, int N) {
  __shared__ int degS[512];
  __shared__ int pS[256];
  __shared__ int curS[512];
  int b = blockIdx.x, t = threadIdx.x;
  int n0 = b << 9, n1 = min(n0 + 512, N);
  int nn = n1 - n0;
  int r0 = bbase[b], r1 = bbase[b + 1];
  degS[t] = 0; degS[t + 256] = 0;
  __syncthreads();
  for (int e = r0 + t; e < r1; e += 256) atomicAdd(&degS[esort[e] & 511], 1);
  __syncthreads();
  int d0 = degS[2 * t], d1 = degS[2 * t + 1];
  int ps = d0 + d1;
  pS[t] = ps;
  __syncthreads();
  for (int off = 1; off < 256; off <<= 1) {
    int add = (t >= off) ? pS[t - off] : 0;
    __syncthreads();
    pS[t] += add;
    __syncthreads();
  }
  int pexcl = pS[t] - ps;  // exclusive pair prefix
  int e0 = pexcl, e1 = pexcl + d0;
  curS[2 * t] = r0 + e0;
  curS[2 * t + 1] = r0 + e1;
  int i0 = 2 * t, i1 = 2 * t + 1;
  if (i0 < nn) {
    rowoff[n0 + i0 + 1] = r0 + e0 + d0;
    node_deg[n0 + i0] = d0;
    dinv[n0 + i0] = rsqrtf((float)d0 + 1.f);
  }
  if (i1 < nn) {
    rowoff[n0 + i1 + 1] = r0 + e1 + d1;
    node_deg[n0 + i1] = d1;
    dinv[n0 + i1] = rsqrtf((float)d1 + 1.f);
  }
  if (b == 0 && t == 0) rowoff[0] = 0;
  __syncthreads();
  for (int e = r0 + t; e < r1; e += 256) {
    int v = esort[e];
    int p = atomicAdd(&curS[v & 511], 1);
    csr_src[p] = v >> 9;
  }
}

// ---------------- per-graph degree stats (wave-uniform fold, ex-scanC) ----------------
static __global__ void nodestats_kernel(const int* __restrict__ node_deg,
                                        const int* __restrict__ batch,
                                        float* gcnt, float* gdsum, unsigned* gdmaxE, int N) {
  int i = blockIdx.x * 256 + threadIdx.x;
  int nd = (i < N) ? node_deg[i] : 0;
  int g = batch[min(i, N - 1)];
  float dv = (float)nd;
  int g0w = __shfl(g, 0);
  int waveLast = blockIdx.x * 256 + ((threadIdx.x >> 6) << 6) + 63;
  bool uni = (waveLast < N) && __all(g == g0w);
  if (uni) {
    float s = dv, mx = dv;
    for (int off = 32; off > 0; off >>= 1) { s += __shfl_down(s, off); mx = fmaxf(mx, __shfl_down(mx, off)); }
    if ((threadIdx.x & 63) == 0) {
      atomicAdd(&gcnt[g0w], 64.f);
      atomicAdd(&gdsum[g0w], s);
      atomicMax(&gdmaxE[g0w], encf(mx));
    }
  } else if (i < N) {
    atomicAdd(&gcnt[g], 1.f);
    atomicAdd(&gdsum[g], dv);
    atomicMax(&gdmaxE[g], encf(dv));
  }
}

// ---------------- GCN aggregation: one WAVE per node, uint4 rows (16 lanes/row, 4 edges/group) ----
// FROZEN at R9 form: compulsory-traffic floor (190MB ~ 8 XCDs x 86% x 25.6MB) at the
// L3 random-line ceiling (~3.8 TB/s) with ~52% VALUBusy. R10's half-split experiment
// REGRESSED (VALU-bound at 74%, FETCH only -12%) — traffic shaping needs VALU headroom.
static __global__ void __launch_bounds__(256) gather_kernel(
    const ushort* __restrict__ xb, const int* __restrict__ rowoff,
    const int* __restrict__ csr_src, const float* __restrict__ dinv,
    ushort* __restrict__ aggB, int N) {
  __shared__ int eS[4][64];
  int t = threadIdx.x, w = t >> 6, l = t & 63;
  int n = blockIdx.x * 4 + w;
  if (n >= N) return;
  int h = l >> 4;            // edge sub-slot 0..3
  int c16 = l & 15;          // 16B column within row (8 bf16)
  int r0 = rowoff[n], r1 = rowoff[n + 1];
  float dn = dinv[n];
  const uint4* xb4 = (const uint4*)xb;   // row stride = 16 uint4
  uint4 xo = xb4[(size_t)n * 16 + c16];  // own (pre-scaled) row
  float acc[8];
#pragma unroll
  for (int i = 0; i < 8; i++) acc[i] = 0.f;
  int pads = 0;
#define ACC8(v) { \
    unsigned u0 = (v).x, u1 = (v).y, u2 = (v).z, u3 = (v).w; \
    acc[0] += uaf(u0 << 16); acc[1] += uaf(u0 & 0xFFFF0000u); \
    acc[2] += uaf(u1 << 16); acc[3] += uaf(u1 & 0xFFFF0000u); \
    acc[4] += uaf(u2 << 16); acc[5] += uaf(u2 & 0xFFFF0000u); \
    acc[6] += uaf(u3 << 16); acc[7] += uaf(u3 & 0xFFFF0000u); }
  for (int j0 = r0; j0 < r1; j0 += 64) {
    int cnt = min(64, r1 - j0);
    int cnt4 = (cnt + 3) & ~3;
    pads += cnt4 - cnt;
    eS[w][l] = (j0 + l < r1) ? csr_src[j0 + l] : n;
    int k = 0;
    for (; k + 16 <= cnt4; k += 16) {  // 4 dwordx4 gathers in flight
      int s0 = eS[w][k + h];
      int s1 = eS[w][k + 4 + h];
      int s2 = eS[w][k + 8 + h];
      int s3 = eS[w][k + 12 + h];
      uint4 v0 = xb4[(size_t)s0 * 16 + c16];
      uint4 v1 = xb4[(size_t)s1 * 16 + c16];
      uint4 v2 = xb4[(size_t)s2 * 16 + c16];
      uint4 v3 = xb4[(size_t)s3 * 16 + c16];
      ACC8(v0); ACC8(v1); ACC8(v2); ACC8(v3);
    }
    if (k + 8 <= cnt4) {
      int s0 = eS[w][k + h];
      int s1 = eS[w][k + 4 + h];
      uint4 v0 = xb4[(size_t)s0 * 16 + c16];
      uint4 v1 = xb4[(size_t)s1 * 16 + c16];
      ACC8(v0); ACC8(v1);
      k += 8;
    }
    if (k < cnt4) {
      int s0 = eS[w][k + h];
      uint4 v0 = xb4[(size_t)s0 * 16 + c16];
      ACC8(v0);
    }
  }
#undef ACC8
#pragma unroll
  for (int i = 0; i < 8; i++) {  // fold 4 edge-slot groups
    acc[i] += __shfl_down(acc[i], 32);
    acc[i] += __shfl_down(acc[i], 16);
  }
  if (l < 16) {
    float wn = 1.f - (float)pads;  // self term minus pad over-count
    float xf[8];
    xf[0] = uaf(xo.x << 16); xf[1] = uaf(xo.x & 0xFFFF0000u);
    xf[2] = uaf(xo.y << 16); xf[3] = uaf(xo.y & 0xFFFF0000u);
    xf[4] = uaf(xo.z << 16); xf[5] = uaf(xo.z & 0xFFFF0000u);
    xf[6] = uaf(xo.w << 16); xf[7] = uaf(xo.w & 0xFFFF0000u);
    unsigned o[4];
#pragma unroll
    for (int i = 0; i < 4; i++) {
      unsigned lo = f2bf(dn * (acc[2 * i] + wn * xf[2 * i]));
      unsigned hi = f2bf(dn * (acc[2 * i + 1] + wn * xf[2 * i + 1]));
      o[i] = lo | (hi << 16);
    }
    uint4 ov; ov.x = o[0]; ov.y = o[1]; ov.z = o[2]; ov.w = o[3];
    ((uint4*)aggB)[(size_t)n * 16 + c16] = ov;
  }
}

// ---------------- gated expert combine + residual (MFMA bf16), 4 waves, 32 cols/wave ----
// Ballot-mask segments; W panel staged to LDS; XCD-chunk-swizzled tile index.
static __global__ void __launch_bounds__(256) expert_kernel(
    const ushort* __restrict__ aggB, const float* __restrict__ x, const int* __restrict__ batch,
    const ushort* __restrict__ W_combT, const float* __restrict__ b_comb,
    ushort* __restrict__ hB, float* bn1s, float* bn1s2, int N) {
  __shared__ __align__(16) ushort aggS[64 * 136];   // 17 KB
  __shared__ __align__(16) ushort wS[128 * 136];    // 34 KB (W panel, per segment)
  __shared__ int bS[64];
  int t = threadIdx.x;
  // ---- XCD-aware bijective tile swizzle (8 XCDs, round-robin hw dispatch) ----
  int nwg = gridDim.x;
  int q = nwg >> 3, r = nwg & 7;
  int xcd = blockIdx.x & 7, ix = blockIdx.x >> 3;
  int tilei = (xcd < r) ? (xcd * (q + 1) + ix) : (r * (q + 1) + (xcd - r) * q + ix);
  int n0 = tilei * 64;
  int tile = min(64, N - n0);
  for (int k = t; k < 64 * 16; k += 256) {  // short8 copies, no convert
    int i = k >> 4, c = (k & 15) * 8;
    short8 v = (short8){0, 0, 0, 0, 0, 0, 0, 0};
    if (i < tile) v = *(const short8*)&aggB[(size_t)(n0 + i) * D + c];
    *(short8*)&aggS[i * 136 + c] = v;
  }
  if (t < 64) bS[t] = batch[min(n0 + t, N - 1)];
  __syncthreads();
  int w = t >> 6, ln = t & 15, quad = (t & 63) >> 4, l64 = t & 63;
  // ---- segment mask: one parallel LDS read + shfl + ballot (all-register after) ----
  int myg = bS[l64];
  int gnext = __shfl_down(myg, 1);
  unsigned long long bmask = __ballot(l64 == 63 || myg != gnext);
  float s[2] = {0.f, 0.f}, s2[2] = {0.f, 0.f};
  int mstart = 0;
  while (mstart < tile) {
    int g = __shfl(myg, mstart);                 // wave-uniform broadcast, no LDS
    int mend = mstart + __ffsll((unsigned long long)(bmask >> mstart));  // 1-based ffs
    if (mend > tile) mend = tile;
    // ---- stage W panel (32 KB) for this segment's graph into LDS ----
    __syncthreads();  // protect wS from previous segment's readers
    const ushort* Wg = W_combT + (size_t)g * 16384;
    for (int k = t; k < 128 * 16; k += 256) {
      int o = k >> 4, c = (k & 15) * 8;
      *(short8*)&wS[o * 136 + c] = *(const short8*)&Wg[(size_t)o * 128 + c];
    }
    __syncthreads();
    f32x4 acc[4][2];
#pragma unroll
    for (int mi = 0; mi < 4; mi++)
#pragma unroll
      for (int ni = 0; ni < 2; ni++) acc[mi][ni] = (f32x4){0.f, 0.f, 0.f, 0.f};
#pragma unroll
    for (int ks = 0; ks < 4; ks++) {
      int kk = ks * 32 + quad * 8;
      short8 a[4], b[2];
#pragma unroll
      for (int mi = 0; mi < 4; mi++) a[mi] = *(const short8*)&aggS[(mi * 16 + ln) * 136 + kk];
#pragma unroll
      for (int ni = 0; ni < 2; ni++) b[ni] = *(const short8*)&wS[(w * 32 + ni * 16 + ln) * 136 + kk];
#pragma unroll
      for (int mi = 0; mi < 4; mi++)
#pragma unroll
        for (int ni = 0; ni < 2; ni++)
          acc[mi][ni] = __builtin_amdgcn_mfma_f32_16x16x32_bf16(a[mi], b[ni], acc[mi][ni], 0, 0, 0);
    }
    float bias[2];
#pragma unroll
    for (int ni = 0; ni < 2; ni++) bias[ni] = b_comb[g * D + w * 32 + ni * 16 + ln];
#pragma unroll
    for (int mi = 0; mi < 4; mi++)
#pragma unroll
      for (int r2_ = 0; r2_ < 4; r2_++) {
        int m = mi * 16 + quad * 4 + r2_;
        if (m >= mstart && m < mend) {
          size_t rowoff_ = (size_t)(n0 + m) * D;
#pragma unroll
          for (int ni = 0; ni < 2; ni++) {
            int o = w * 32 + ni * 16 + ln;
            float hv = x[rowoff_ + o] + acc[mi][ni][r2_] + bias[ni];
            hB[rowoff_ + o] = f2bf(hv);
            s[ni] += hv; s2[ni] += hv * hv;
          }
        }
      }
    mstart = mend;
  }
#pragma unroll
  for (int ni = 0; ni < 2; ni++) {
    s[ni] += __shfl_down(s[ni], 32);  s[ni] += __shfl_down(s[ni], 16);
    s2[ni] += __shfl_down(s2[ni], 32); s2[ni] += __shfl_down(s2[ni], 16);
  }
  if (quad == 0) {
    int slot = (tilei & (NREP - 1)) * D;
#pragma unroll
    for (int ni = 0; ni < 2; ni++) {
      int o = w * 32 + ni * 16 + ln;
      atomicAdd(&bn1s[slot + o], s[ni]);
      atomicAdd(&bn1s2[slot + o], s2[ni]);
    }
  }
}

// ---------------- bn finalize: reduce 64 replicas -> fused scale/shift ----------------
static __global__ void bnfin_kernel(const float* s, const float* s2,
                                    const float* __restrict__ g, const float* __restrict__ b,
                                    float* sc, float* sh, float invN) {
  int t = threadIdx.x;
  if (t < D) {
    float st = 0.f, s2t = 0.f;
    for (int k = 0; k < NREP; k++) { st += s[k * D + t]; s2t += s2[k * D + t]; }
    float m = st * invN;
    float var = s2t * invN - m * m;
    float rstd = rsqrtf(var + EPSV);
    float scv = rstd * g[t];
    sc[t] = scv;
    sh[t] = b[t] - m * scv;
  }
}

// ---------------- FFN (MFMA bf16), M=64, 8 waves, in-place on hB ----------------
static __global__ void __launch_bounds__(512, 4) ffn_kernel(
    ushort* __restrict__ hB, const float* __restrict__ sc1, const float* __restrict__ sh1,
    const ushort* __restrict__ w1t, const float* __restrict__ fb1,
    const ushort* __restrict__ w2t, const float* __restrict__ fb2,
    float* bn2s, float* bn2s2, int N) {
  __shared__ __align__(16) ushort kvnS[64 * 136];   // 17 KB
  __shared__ __align__(16) ushort hidS[64 * 264];   // 34 KB
  int t = threadIdx.x, n0 = blockIdx.x * 64;
  int tile = min(64, N - n0);
  for (int k = t; k < 64 * 16; k += 512) {   // uint4 loads: 8 bf16 per iteration
    int i = k >> 4, c = (k & 15) * 8;
    ushort o[8];
    if (i < tile) {
      uint4 hv = *(const uint4*)&hB[(size_t)(n0 + i) * D + c];
      unsigned uu[4] = {hv.x, hv.y, hv.z, hv.w};
#pragma unroll
      for (int j = 0; j < 4; j++) {
        float lo = uaf(uu[j] << 16) * sc1[c + 2 * j] + sh1[c + 2 * j];
        float hi = uaf(uu[j] & 0xFFFF0000u) * sc1[c + 2 * j + 1] + sh1[c + 2 * j + 1];
        o[2 * j] = f2bf(lo); o[2 * j + 1] = f2bf(hi);
      }
    } else {
#pragma unroll
      for (int j = 0; j < 8; j++) o[j] = 0;
    }
    *(short8*)&kvnS[i * 136 + c] = *(short8*)o;
  }
  __syncthreads();
  int w = t >> 6, ln = t & 15, quad = (t & 63) >> 4;
  // ---- GEMM1: hidden[64x256] = kvn[64x128] @ w1[128x256]; wave w -> cols w*32..w*32+31
  f32x4 acc1[4][2];
#pragma unroll
  for (int mi = 0; mi < 4; mi++)
#pragma unroll
    for (int ni = 0; ni < 2; ni++) acc1[mi][ni] = (f32x4){0.f, 0.f, 0.f, 0.f};
#pragma unroll
  for (int ks = 0; ks < 4; ks++) {
    int kk = ks * 32 + quad * 8;
    short8 a[4], b[2];
#pragma unroll
    for (int mi = 0; mi < 4; mi++) a[mi] = *(const short8*)&kvnS[(mi * 16 + ln) * 136 + kk];
#pragma unroll
    for (int ni = 0; ni < 2; ni++) b[ni] = *(const short8*)&w1t[(size_t)(w * 32 + ni * 16 + ln) * 128 + kk];
#pragma unroll
    for (int mi = 0; mi < 4; mi++)
#pragma unroll
      for (int ni = 0; ni < 2; ni++)
        acc1[mi][ni] = __builtin_amdgcn_mfma_f32_16x16x32_bf16(a[mi], b[ni], acc1[mi][ni], 0, 0, 0);
  }
  float bias1[2];
#pragma unroll
  for (int ni = 0; ni < 2; ni++) bias1[ni] = fb1[w * 32 + ni * 16 + ln];
#pragma unroll
  for (int mi = 0; mi < 4; mi++)
#pragma unroll
    for (int ni = 0; ni < 2; ni++)
#pragma unroll
      for (int r = 0; r < 4; r++) {
        int mrow = mi * 16 + quad * 4 + r;
        int j = w * 32 + ni * 16 + ln;
        hidS[mrow * 264 + j] = f2bf(fmaxf(acc1[mi][ni][r] + bias1[ni], 0.f));
      }
  __syncthreads();
  // ---- GEMM2: out[64x128] = hidden[64x256] @ w2[256x128]; wave w -> cols w*16..w*16+15
  int o = w * 16 + ln;
  f32x4 acc2[4];
#pragma unroll
  for (int mi = 0; mi < 4; mi++) acc2[mi] = (f32x4){0.f, 0.f, 0.f, 0.f};
#pragma unroll
  for (int ks = 0; ks < 8; ks++) {
    int kk = ks * 32 + quad * 8;
    short8 a[4], b;
#pragma unroll
    for (int mi = 0; mi < 4; mi++) a[mi] = *(const short8*)&hidS[(mi * 16 + ln) * 264 + kk];
    b = *(const short8*)&w2t[(size_t)o * 256 + kk];
#pragma unroll
    for (int mi = 0; mi < 4; mi++)
      acc2[mi] = __builtin_amdgcn_mfma_f32_16x16x32_bf16(a[mi], b, acc2[mi], 0, 0, 0);
  }
  float bias2 = fb2[o];
  float s = 0.f, s2 = 0.f;
#pragma unroll
  for (int mi = 0; mi < 4; mi++)
#pragma unroll
    for (int r = 0; r < 4; r++) {
      int mrow = mi * 16 + quad * 4 + r;
      if (mrow < tile) {
        size_t ro = (size_t)(n0 + mrow) * D;
        float v = bf2f(kvnS[mrow * 136 + o]) + acc2[mi][r] + bias2;
        hB[ro + o] = f2bf(v);  // in-place: tile already staged in kvnS
        s += v; s2 += v * v;
      }
    }
  s += __shfl_down(s, 32);  s += __shfl_down(s, 16);
  s2 += __shfl_down(s2, 32); s2 += __shfl_down(s2, 16);
  if (quad == 0) {
    int slot = (blockIdx.x & (NREP - 1)) * D;
    atomicAdd(&bn2s[slot + o], s);
    atomicAdd(&bn2s2[slot + o], s2);
  }
}

// ---------------- final bn2 apply: bf16 in -> fp32 out, 8 elems/thread ----------------
static __global__ void bnapply_kernel(const ushort* __restrict__ hB, float* __restrict__ out,
                                      const float* __restrict__ sc, const float* __restrict__ sh,
                                      int total8) {
  int i = blockIdx.x * 256 + threadIdx.x;  // 8-element groups
  if (i < total8) {
    int c = (i * 8) & 127;
    uint4 hv = ((const uint4*)hB)[i];
    unsigned uu[4] = {hv.x, hv.y, hv.z, hv.w};
    float4 o0, o1;
    o0.x = uaf(uu[0] << 16) * sc[c] + sh[c];
    o0.y = uaf(uu[0] & 0xFFFF0000u) * sc[c + 1] + sh[c + 1];
    o0.z = uaf(uu[1] << 16) * sc[c + 2] + sh[c + 2];
    o0.w = uaf(uu[1] & 0xFFFF0000u) * sc[c + 3] + sh[c + 3];
    o1.x = uaf(uu[2] << 16) * sc[c + 4] + sh[c + 4];
    o1.y = uaf(uu[2] & 0xFFFF0000u) * sc[c + 5] + sh[c + 5];
    o1.z = uaf(uu[3] << 16) * sc[c + 6] + sh[c + 6];
    o1.w = uaf(uu[3] & 0xFFFF0000u) * sc[c + 7] + sh[c + 7];
    ((float4*)out)[i * 2] = o0;
    ((float4*)out)[i * 2 + 1] = o1;
  }
}

extern "C" void kernel_launch(void* const* d_in, const int* in_sizes, int n_in,
                              void* d_out, int out_size, void* d_ws, size_t ws_size,
                              hipStream_t stream) {
  (void)n_in; (void)out_size; (void)ws_size;
  const float* x    = (const float*)d_in[0];
  const int*   ei   = (const int*)d_in[1];
  const int*   batch= (const int*)d_in[2];
  const float* temp = (const float*)d_in[3];
  const float* rw1  = (const float*)d_in[4];
  const float* rb1  = (const float*)d_in[5];
  const float* rw2  = (const float*)d_in[6];
  const float* rb2  = (const float*)d_in[7];
  const float* rw3  = (const float*)d_in[8];
  const float* rb3  = (const float*)d_in[9];
  const float* ew   = (const float*)d_in[10];
  const float* eb   = (const float*)d_in[11];
  const float* bn1g = (const float*)d_in[12];
  const float* bn1b = (const float*)d_in[13];
  const float* fw1  = (const float*)d_in[14];
  const float* fb1  = (const float*)d_in[15];
  const float* fw2  = (const float*)d_in[16];
  const float* fb2  = (const float*)d_in[17];
  const float* bn2g = (const float*)d_in[18];
  const float* bn2b = (const float*)d_in[19];

  int N = in_sizes[0] / D;
  int E = in_sizes[1] / 2;
  const int* src = ei;
  const int* dst = ei + E;

  // d_out doubles as scratch: x_bf | aggB (2 x N*D*2 bytes = exactly out size);
  // both dead before bnapply overwrites d_out with the fp32 result.
  ushort* x_bf = (ushort*)d_out;
  ushort* aggB = (ushort*)((char*)d_out + (size_t)N * D * 2);

  char* p = (char*)d_ws;
  auto alloc = [&](size_t bytes) -> void* {
    void* r = (void*)p;
    p += (bytes + 255) & ~(size_t)255;
    return r;
  };
  int NB = (N + 511) >> 9;  // 512-node buckets (assumes NB <= 256)
  int*   node_deg = (int*)alloc((size_t)N * 4);
  int*   rowoff   = (int*)alloc(((size_t)N + 1) * 4);
  int*   csr_src  = (int*)alloc((size_t)E * 4);
  int*   esort    = (int*)alloc((size_t)E * 4);
  int*   bcnt     = (int*)alloc(256 * 4);
  int*   bbase    = (int*)alloc(257 * 4);
  int*   bcur     = (int*)alloc(256 * 4);
  float* dinv     = (float*)alloc((size_t)N * 4);
  ushort* hB      = (ushort*)alloc((size_t)N * D * 2);
  float* gsum     = (float*)alloc((size_t)B * D * 4);
  unsigned* gmaxE = (unsigned*)alloc((size_t)B * D * 4);
  float* gcnt     = (float*)alloc((size_t)B * 4);
  float* gdsum    = (float*)alloc((size_t)B * 4);
  unsigned* gdmaxE= (unsigned*)alloc((size_t)B * 4);
  float* gates    = (float*)alloc((size_t)B * 4 * 4);
  float* b_comb   = (float*)alloc((size_t)B * D * 4);
  float* bn1s     = (float*)alloc((size_t)NREP * D * 4);
  float* bn1s2    = (float*)alloc((size_t)NREP * D * 4);
  float* sc1      = (float*)alloc(D * 4);
  float* sh1      = (float*)alloc(D * 4);
  float* bn2s     = (float*)alloc((size_t)NREP * D * 4);
  float* bn2s2    = (float*)alloc((size_t)NREP * D * 4);
  float* sc2      = (float*)alloc(D * 4);
  float* sh2      = (float*)alloc(D * 4);
  ushort* W_combT = (ushort*)alloc((size_t)B * D * D * 2);
  ushort* w1t     = (ushort*)alloc((size_t)D * 256 * 2);
  ushort* w2t     = (ushort*)alloc((size_t)D * 256 * 2);

  // setup (init + weight prep: pure disjoint writes) -> bhist AFTER (reads zeroed bcnt)
  int nbInit = (N + 255) / 256;
  setup_kernel<<<nbInit + 128, 256, 0, stream>>>(
      bcnt, bn1s, bn1s2, bn2s, bn2s2, gsum, gmaxE, gcnt, gdsum, gdmaxE,
      fw1, fw2, w1t, w2t, N, nbInit);
  bhist_kernel<<<(E + 4095) / 4096, 256, 0, stream>>>(dst, bcnt, E);
  bscan_kernel<<<1, 256, 0, stream>>>(bcnt, bbase, bcur);
  fillA_kernel<<<(E + 4095) / 4096, 256, 0, stream>>>(src, dst, bcur, esort, E);
  fillB_kernel<<<NB, 256, 0, stream>>>(esort, bbase, rowoff, node_deg, dinv, csr_src, N);
  nodestats_kernel<<<(N + 255) / 256, 256, 0, stream>>>(node_deg, batch, gcnt, gdsum, gdmaxE, N);
  // statspart needs dinv (x_bf is pre-scaled by dinv)
  statspart_kernel<<<(N + 31) / 32, 128, 0, stream>>>(x, batch, dinv, gsum, gmaxE, x_bf, N);
  router_kernel<<<B, 128, 0, stream>>>(gsum, gmaxE, gcnt, gdsum, gdmaxE,
                                       rw1, rb1, rw2, rb2, rw3, rb3, temp, gates);
  wcomb_kernel<<<B, 256, 0, stream>>>(gates, ew, eb, W_combT, b_comb);
  gather_kernel<<<(N + 3) / 4, 256, 0, stream>>>(x_bf, rowoff, csr_src, dinv, aggB, N);
  int nb64 = (N + 63) / 64;
  expert_kernel<<<nb64, 256, 0, stream>>>(aggB, x, batch, W_combT, b_comb, hB, bn1s, bn1s2, N);
  bnfin_kernel<<<1, 128, 0, stream>>>(bn1s, bn1s2, bn1g, bn1b, sc1, sh1, 1.0f / (float)N);
  ffn_kernel<<<nb64, 512, 0, stream>>>(hB, sc1, sh1, w1t, fb1, w2t, fb2, bn2s, bn2s2, N);
  bnfin_kernel<<<1, 128, 0, stream>>>(bn2s, bn2s2, bn2g, bn2b, sc2, sh2, 1.0f / (float)N);
  int total8 = N * D / 8;
  bnapply_kernel<<<(total8 + 255) / 256, 256, 0, stream>>>(hB, (float*)d_out, sc2, sh2, total8);
}